// Round 7
// baseline (486.984 us; speedup 1.0000x reference)
//
#include <hip/hip_runtime.h>
#include <stdint.h>

#define NS 4096
#define DIM 2048
#define MARGINF 0.3f

typedef __bf16 bf16x8 __attribute__((ext_vector_type(8)));
typedef float floatx4 __attribute__((ext_vector_type(4)));

#define GLOBAL_AS __attribute__((address_space(1)))
#define LDS_AS __attribute__((address_space(3)))

__device__ __forceinline__ unsigned short f2bf_rne(float x) {
  unsigned u = __float_as_uint(x);
  u += 0x7FFFu + ((u >> 16) & 1u);
  return (unsigned short)(u >> 16);
}
__device__ __forceinline__ float bf2f(unsigned short b) {
  return __uint_as_float(((unsigned)b) << 16);
}

// gemm geometry (R2-proven: 77 us, ~920 TF square-equivalent = m97 ceiling).
// Deep in-block pipelining on this geometry is a proven dead end (R3; m232).
#define BM 128
#define BCN 64           // tile cols
#define BKE 64           // K elems staged per iter (128 B per row)
#define NBLK 1056        // == tile count; static blockIdx->tile map (XCD swizzle)

__device__ __forceinline__ void async16(const void* g, void* l) {
  __builtin_amdgcn_global_load_lds((GLOBAL_AS unsigned int*)g, (LDS_AS unsigned int*)l,
                                   16, 0, 0);
}

// tile id -> (ry, cx); cum(y) = y*(65-y) tiles precede row-chunk y; XCD swizzle 8x132
__device__ __forceinline__ void tile_decode(int tt, int& ry, int& cx) {
  const int t = (tt & 7) * 132 + (tt >> 3);
  int y = (int)((65.0f - sqrtf((float)(4225 - 4 * t))) * 0.5f);
  while ((y + 1) * (64 - y) <= t) ++y;   // cum(y+1) = (y+1)*(64-y)
  while (y * (65 - y) > t) --y;
  ry = y;
  cx = 2 * y + (t - y * (65 - y));
}

// R7: manual grid barrier (graph-capture-safe, unlike hipLaunchCooperativeKernel
// which the harness rejected in R6 -> out==0). Monotone arrive counter, reset by
// a captured hipMemsetAsync before the kernel. Residency proof: 1056 blocks x
// 25.1 KB LDS -> 6/CU LDS-limit; launch_bounds(128,3) -> VGPR<=170 -> 6/CU
// wave-limit; capacity 1536 >= 1056, so all blocks co-resident and the spin
// cannot deadlock. Release fence before arrive; acquire fence (L1 inv) after.
__device__ __forceinline__ void grid_sync(unsigned* bar, unsigned target) {
  __syncthreads();
  if (threadIdx.x == 0) {
    __threadfence();                       // release (drain stores to L2)
    atomicAdd(bar, 1u);
    while (__hip_atomic_load(bar, __ATOMIC_RELAXED, __HIP_MEMORY_SCOPE_AGENT) < target)
      __builtin_amdgcn_s_sleep(16);
  }
  __syncthreads();
  __threadfence();                         // acquire (invalidate L1 on every thread)
}

__global__ __launch_bounds__(128, 3) void fused_kernel(
    const float* __restrict__ X, unsigned short* __restrict__ Xbf,
    float* __restrict__ sq, const int* __restrict__ targets,
    const float* __restrict__ LF, unsigned long long* __restrict__ posP,
    unsigned long long* __restrict__ negP, float2* __restrict__ parts,
    unsigned* __restrict__ bar, float* __restrict__ out) {
  __shared__ __align__(16) union SMem {
    struct { unsigned short Ab[BM * BKE]; unsigned short Bb[BCN * BKE]; } g;  // 24 KB
    struct { float bufA[2][1024]; float bufPN[2][2048];
             float dmP[2][64]; float dmN[2][64]; float gt[2]; float lt[2]; } d;  // ~25 KB
    float red[4];
  } sm;
  const int tid = threadIdx.x;
  const int lane = tid & 63;
  const int w = tid >> 6;          // wave 0..1
  const int b = blockIdx.x;

  // ---------------- phase 1: convert + row norms + init (blocks 0..1023) ----------
  if (b < 1024) {
#pragma unroll
    for (int rr = 0; rr < 2; ++rr) {
      const int row = b * 4 + w * 2 + rr;
      const float4* xr = (const float4*)(X + (size_t)row * DIM);
      ushort4* br = (ushort4*)(Xbf + (size_t)row * DIM);
      float s = 0.f;
#pragma unroll
      for (int i = 0; i < 8; ++i) {
        float4 v = xr[lane + i * 64];
        ushort4 o;
        o.x = f2bf_rne(v.x); o.y = f2bf_rne(v.y);
        o.z = f2bf_rne(v.z); o.w = f2bf_rne(v.w);
        // norm of the ROUNDED values so d2 is consistent with the MFMA dot
        float b0 = bf2f(o.x), b1 = bf2f(o.y), b2 = bf2f(o.z), b3 = bf2f(o.w);
        s += b0 * b0 + b1 * b1 + b2 * b2 + b3 * b3;
        br[lane + i * 64] = o;
      }
#pragma unroll
      for (int m = 32; m > 0; m >>= 1) s += __shfl_down(s, m, 64);
      if (lane == 0) {
        sq[row] = s;
        posP[row] = 0ULL;
        negP[row] = ~0ULL;
      }
    }
  }
  grid_sync(bar, NBLK);

  // ---------------- phase 2: Gram GEMM + mining (R2-proven body, tile = blockIdx) --
  {
    int ry, cx;
    tile_decode(b, ry, cx);
    const int r0 = ry * BM;
    const int c0 = cx * BCN;
    const int quad = lane >> 4;
    const int ml = lane & 15;
    const int sx = ml & 7;

    floatx4 acc[4][4];
#pragma unroll
    for (int i = 0; i < 4; ++i)
#pragma unroll
      for (int j = 0; j < 4; ++j)
#pragma unroll
        for (int k = 0; k < 4; ++k) acc[i][j][k] = 0.f;

    // staging (verified conflict-free): chunk c of row R at slot c ^ (R&7);
    // DMA lane -> (row lane>>3, slot lane&7); each async16 = 8 rows x 128 B.
    const int r_rel = lane >> 3;
    const int c_g = (lane & 7) ^ r_rel;
    const unsigned short* gA = Xbf + (size_t)(r0 + w * 64 + r_rel) * DIM + c_g * 8;
    const unsigned short* gB = Xbf + (size_t)(c0 + w * 32 + r_rel) * DIM + c_g * 8;
    unsigned short* lA = sm.g.Ab + w * 64 * BKE;
    unsigned short* lB = sm.g.Bb + w * 32 * BKE;

    for (int k0 = 0; k0 < DIM; k0 += BKE) {
      __syncthreads();
#pragma unroll
      for (int q = 0; q < 8; ++q)
        async16(gA + (size_t)(q * 8) * DIM + k0, lA + q * 8 * BKE);
#pragma unroll
      for (int q = 0; q < 4; ++q)
        async16(gB + (size_t)(q * 8) * DIM + k0, lB + q * 8 * BKE);
      __syncthreads();   // vmcnt(0) drain
#pragma unroll
      for (int h = 0; h < 2; ++h) {
        const int slot = ((h << 2) + quad) ^ sx;
        bf16x8 af[4], bfr[4];
#pragma unroll
        for (int i = 0; i < 4; ++i)
          af[i] = *(const bf16x8*)(sm.g.Ab + ((w * 64 + i * 16 + ml) * BKE) + slot * 8);
#pragma unroll
        for (int j = 0; j < 4; ++j)
          bfr[j] = *(const bf16x8*)(sm.g.Bb + ((j * 16 + ml) * BKE) + slot * 8);
#pragma unroll
        for (int i = 0; i < 4; ++i)
#pragma unroll
          for (int j = 0; j < 4; ++j)
            acc[i][j] = __builtin_amdgcn_mfma_f32_16x16x32_bf16(af[i], bfr[j], acc[i][j], 0, 0, 0);
      }
    }

    // epilogue A: row-direction mining. C/D layout: col = lane&15, row = quad*4+reg.
    const int cl = ml;
#pragma unroll
    for (int i = 0; i < 4; ++i) {
#pragma unroll
      for (int rg = 0; rg < 4; ++rg) {
        const int gr = r0 + w * 64 + i * 16 + quad * 4 + rg;
        const int tgt_r = targets[gr];
        const float sqr = sq[gr];
        unsigned long long pm = 0ULL;
        unsigned long long nm = ~0ULL;
#pragma unroll
        for (int j = 0; j < 4; ++j) {
          const int gc = c0 + j * 16 + cl;
          const float d2 = sqr + sq[gc] - 2.0f * acc[i][j][rg];
          const float dist = sqrtf(fmaxf(d2, 1e-12f));
          const unsigned long long ph = ((unsigned long long)__float_as_uint(dist)) << 32;
          if (targets[gc] == tgt_r) {
            // argmax first-index tiebreak: larger (4095-gc) == smaller gc wins
            unsigned long long cand = ph | (unsigned)(4095 - gc);
            pm = pm > cand ? pm : cand;
          } else {
            unsigned long long cand = ph | (unsigned)gc;
            nm = nm < cand ? nm : cand;
          }
        }
#pragma unroll
        for (int m = 1; m < 16; m <<= 1) {
          unsigned long long pmo = __shfl_xor(pm, m, 64);
          unsigned long long nmo = __shfl_xor(nm, m, 64);
          pm = pm > pmo ? pm : pmo;
          nm = nm < nmo ? nm : nmo;
        }
        if (cl == 0) {
          atomicMax(&posP[gr], pm);
          atomicMin(&negP[gr], nm);
        }
      }
    }

    // epilogue B: transposed mining (only when col-range outside row-range)
    if (cx >= 2 * ry + 2) {
#pragma unroll
      for (int j = 0; j < 4; ++j) {
        const int gc = c0 + j * 16 + cl;
        const int tgt_c = targets[gc];
        const float sqc = sq[gc];
        unsigned long long pm = 0ULL;
        unsigned long long nm = ~0ULL;
#pragma unroll
        for (int i = 0; i < 4; ++i) {
#pragma unroll
          for (int rg = 0; rg < 4; ++rg) {
            const int gr = r0 + w * 64 + i * 16 + quad * 4 + rg;
            const float d2 = sq[gr] + sqc - 2.0f * acc[i][j][rg];
            const float dist = sqrtf(fmaxf(d2, 1e-12f));
            const unsigned long long ph = ((unsigned long long)__float_as_uint(dist)) << 32;
            if (targets[gr] == tgt_c) {
              unsigned long long cand = ph | (unsigned)(4095 - gr);
              pm = pm > cand ? pm : cand;
            } else {
              unsigned long long cand = ph | (unsigned)gr;
              nm = nm < cand ? nm : cand;
            }
          }
        }
#pragma unroll
        for (int m = 16; m < 64; m <<= 1) {
          unsigned long long pmo = __shfl_xor(pm, m, 64);
          unsigned long long nmo = __shfl_xor(nm, m, 64);
          pm = pm > pmo ? pm : pmo;
          nm = nm < nmo ? nm : nmo;
        }
        if (quad == 0) {
          atomicMax(&posP[gc], pm);
          atomicMin(&negP[gc], nm);
        }
      }
    }
  }
  grid_sync(bar, 2 * NBLK);

  // ---------------- phase 3: local DTW (blocks 0..1023, 2 anchors per wave) -------
  if (b < 1024) {
    float gsum = 0.f, lsum = 0.f;
    for (int it = 0; it < 2; ++it) {
      const int a = (b * 2 + w) * 2 + it;
      const unsigned long long pp =
          __hip_atomic_load(&posP[a], __ATOMIC_RELAXED, __HIP_MEMORY_SCOPE_AGENT);
      const unsigned long long nn =
          __hip_atomic_load(&negP[a], __ATOMIC_RELAXED, __HIP_MEMORY_SCOPE_AGENT);
      const int p_ind = 4095 - (int)(pp & 0xFFFFFFFFULL);
      const int n_ind = (int)(nn & 0xFFFFFFFFULL);
      const float dist_ap = __uint_as_float((unsigned)(pp >> 32));
      const float dist_an = __uint_as_float((unsigned)(nn >> 32));

      const float4* ga = (const float4*)(LF + (size_t)a * 1024);
      const float4* gp = (const float4*)(LF + (size_t)p_ind * 1024);
      const float4* gn = (const float4*)(LF + (size_t)n_ind * 1024);
      float4* la = (float4*)sm.d.bufA[w];
      float4* lpn = (float4*)sm.d.bufPN[w];
#pragma unroll
      for (int i = 0; i < 4; ++i) {
        const int idx = lane + i * 64;
        la[idx] = ga[idx];
        float4 p = gp[idx];
        float4 n = gn[idx];
        // element e=idx*4+k of P goes to pn[2e], of N to pn[2e+1]
        lpn[2 * idx] = make_float4(p.x, n.x, p.y, n.y);
        lpn[2 * idx + 1] = make_float4(p.z, n.z, p.w, n.w);
      }
      __syncthreads();
      const int t1 = lane >> 3, t2 = lane & 7;
      float sp = 0.f, sn = 0.f;
#pragma unroll 8
      for (int d = 0; d < 128; ++d) {
        float xa = sm.d.bufA[w][d * 8 + t1];
        float2 pnv = *(const float2*)&sm.d.bufPN[w][2 * (d * 8 + t2)];
        float e1 = xa - pnv.x; sp += e1 * e1;
        float e2 = xa - pnv.y; sn += e2 * e2;
      }
      sm.d.dmP[w][lane] = tanhf(0.5f * sqrtf(fmaxf(sp, 1e-12f)));  // == (e^d-1)/(e^d+1)
      sm.d.dmN[w][lane] = tanhf(0.5f * sqrtf(fmaxf(sn, 1e-12f)));
      __syncthreads();
      // two serial 8x8 DPs per wave run concurrently on lanes 0 and 1
      if (lane < 2) {
        const float* dm = (lane == 0) ? sm.d.dmP[w] : sm.d.dmN[w];
        float row[8];
        row[0] = dm[0];
#pragma unroll
        for (int j = 1; j < 8; ++j) row[j] = row[j - 1] + dm[j];
#pragma unroll
        for (int i = 1; i < 8; ++i) {
          row[0] = row[0] + dm[i * 8];
#pragma unroll
          for (int j = 1; j < 8; ++j) row[j] = fminf(row[j], row[j - 1]) + dm[i * 8 + j];
        }
        if (lane == 0) sm.d.dmP[w][0] = row[7];   // reuse LDS slot to pass ap
        else sm.d.dmN[w][0] = row[7];             // an
      }
      __syncthreads();
      if (lane == 0) {
        gsum += fmaxf(dist_ap - dist_an + MARGINF, 0.f);
        lsum += fmaxf(sm.d.dmP[w][0] - sm.d.dmN[w][0] + MARGINF, 0.f);
      }
      __syncthreads();
    }
    if (lane == 0) { sm.d.gt[w] = gsum; sm.d.lt[w] = lsum; }
    __syncthreads();
    if (tid == 0)
      parts[b] = make_float2(sm.d.gt[0] + sm.d.gt[1], sm.d.lt[0] + sm.d.lt[1]);
  }
  grid_sync(bar, 3 * NBLK);

  // ---------------- phase 4: block 0 reduces 1024 partials, writes out ------------
  if (b == 0) {
    float g = 0.f, l = 0.f;
#pragma unroll
    for (int i = 0; i < 8; ++i) {
      float2 v = parts[tid + i * 128];
      g += v.x; l += v.y;
    }
#pragma unroll
    for (int m = 32; m > 0; m >>= 1) {
      g += __shfl_down(g, m, 64);
      l += __shfl_down(l, m, 64);
    }
    if (lane == 0) { sm.red[w] = g; sm.red[w + 2] = l; }
    __syncthreads();
    if (tid == 0) {
      out[0] = (sm.red[0] + sm.red[1]) * (1.0f / 4096.0f);
      out[1] = (sm.red[2] + sm.red[3]) * (1.0f / 4096.0f);
    }
  }
}

extern "C" void kernel_launch(void* const* d_in, const int* in_sizes, int n_in,
                              void* d_out, int out_size, void* d_ws, size_t ws_size,
                              hipStream_t stream) {
  const float* X = (const float*)d_in[0];
  const int* targets = (const int*)d_in[1];
  const float* LF = (const float*)d_in[2];
  float* out = (float*)d_out;

  char* ws = (char*)d_ws;
  size_t off = 0;
  unsigned short* Xbf = (unsigned short*)(ws + off); off += (size_t)NS * DIM * 2;  // 16 MB
  float* sq = (float*)(ws + off); off += (size_t)NS * 4;
  off = (off + 255) & ~(size_t)255;
  unsigned long long* posP = (unsigned long long*)(ws + off); off += (size_t)NS * 8;
  unsigned long long* negP = (unsigned long long*)(ws + off); off += (size_t)NS * 8;
  float2* parts = (float2*)(ws + off); off += (size_t)1024 * 8;
  unsigned* bar = (unsigned*)(ws + off); off += 256;

  hipMemsetAsync(bar, 0, 256, stream);   // reset barrier counter (captured in graph)
  fused_kernel<<<NBLK, 128, 0, stream>>>(X, Xbf, sq, targets, LF, posP, negP,
                                         parts, bar, out);
}

// Round 8
// 204.403 us; speedup vs baseline: 2.3825x; 2.3825x over previous
//
#include <hip/hip_runtime.h>
#include <stdint.h>
#include <string.h>

#define NS 4096
#define DIM 2048
#define MARGINF 0.3f

typedef __bf16 bf16x8 __attribute__((ext_vector_type(8)));
typedef float floatx4 __attribute__((ext_vector_type(4)));

#define GLOBAL_AS __attribute__((address_space(1)))
#define LDS_AS __attribute__((address_space(3)))

__device__ __forceinline__ unsigned short f2bf_rne(float x) {
  unsigned u = __float_as_uint(x);
  u += 0x7FFFu + ((u >> 16) & 1u);
  return (unsigned short)(u >> 16);
}
__device__ __forceinline__ float bf2f(unsigned short b) {
  return __uint_as_float(((unsigned)b) << 16);
}

// ---------------- kernel 1: fp32 -> bf16 convert + row norms + init ----------------
// R5-proven body (one row per wave, pure-shfl, no LDS/barriers). Also re-zeroes the
// fused kernel's bar/cnt each run (graph-replay-safe). The kernel boundary after
// this launch is the bulk release fence for Xbf/sq -- free, done by the runtime.
__global__ __launch_bounds__(256) void prep_kernel(
    const float* __restrict__ X, unsigned short* __restrict__ Xbf,
    float* __restrict__ sq, unsigned long long* __restrict__ posP,
    unsigned long long* __restrict__ negP, unsigned* __restrict__ bar,
    unsigned* __restrict__ cnt) {
  const int w = threadIdx.x >> 6, lane = threadIdx.x & 63;
  const int row = blockIdx.x * 4 + w;
  if (blockIdx.x == 0 && threadIdx.x == 0) { *bar = 0u; *cnt = 0u; }
  const float4* xr = (const float4*)(X + (size_t)row * DIM);
  ushort4* br = (ushort4*)(Xbf + (size_t)row * DIM);
  float s = 0.f;
#pragma unroll
  for (int i = 0; i < 8; ++i) {
    float4 v = xr[lane + i * 64];
    ushort4 o;
    o.x = f2bf_rne(v.x); o.y = f2bf_rne(v.y);
    o.z = f2bf_rne(v.z); o.w = f2bf_rne(v.w);
    // norm of the ROUNDED values so d2 is consistent with the MFMA dot
    float b0 = bf2f(o.x), b1 = bf2f(o.y), b2 = bf2f(o.z), b3 = bf2f(o.w);
    s += b0 * b0 + b1 * b1 + b2 * b2 + b3 * b3;
    br[lane + i * 64] = o;
  }
#pragma unroll
  for (int m = 32; m > 0; m >>= 1) s += __shfl_down(s, m, 64);
  if (lane == 0) {
    sq[row] = s;
    posP[row] = 0ULL;
    negP[row] = ~0ULL;
  }
}

// gemm geometry (R2-proven: 77 us, ~920 TF square-equivalent = m97 ceiling).
// Deep in-block pipelining on this geometry is a proven dead end (R3; m232).
#define BM 128
#define BCN 64           // tile cols
#define BKE 64           // K elems staged per iter (128 B per row)
#define NBLK 1056        // == tile count; static blockIdx->tile map (XCD swizzle)

__device__ __forceinline__ void async16(const void* g, void* l) {
  __builtin_amdgcn_global_load_lds((GLOBAL_AS unsigned int*)g, (LDS_AS unsigned int*)l,
                                   16, 0, 0);
}

// tile id -> (ry, cx); cum(y) = y*(65-y) tiles precede row-chunk y; XCD swizzle 8x132
__device__ __forceinline__ void tile_decode(int tt, int& ry, int& cx) {
  const int t = (tt & 7) * 132 + (tt >> 3);
  int y = (int)((65.0f - sqrtf((float)(4225 - 4 * t))) * 0.5f);
  while ((y + 1) * (64 - y) <= t) ++y;   // cum(y+1) = (y+1)*(64-y)
  while (y * (65 - y) > t) --y;
  ry = y;
  cx = 2 * y + (t - y * (65 - y));
}

// ---------------- kernel 2: fused GEMM+mine -> barrier -> DTW -> finalize ----------
// R8: ONE interior barrier, ZERO threadfences (R7's 350 us lesson: per-thread
// device-scope fences serialize in the TCC). Legal because the only data crossing
// the barrier is posP/negP -- written AND read via device-scope atomics, which are
// coherent at the memory-side atomic unit. __syncthreads drains vmcnt (mining
// atomics complete) before the arrive-add; dtw reads posP/negP with agent-scope
// atomic loads (bypass stale L1/L2). parts/finalize use the R1-3-proven cnt
// pattern with 8-byte agent atomic stores/loads -- again no cache flushes.
// Residency proof (R7 empirically passed at same footprint): 26 KB LDS -> 6/CU,
// launch_bounds(128,3) -> 6/CU; capacity 1536 >= 1056.
__global__ __launch_bounds__(128, 3) void gemm_dtw_kernel(
    const unsigned short* __restrict__ Xbf, const float* __restrict__ sq,
    const int* __restrict__ targets, const float* __restrict__ LF,
    unsigned long long* __restrict__ posP, unsigned long long* __restrict__ negP,
    unsigned long long* __restrict__ parts, unsigned* __restrict__ bar,
    unsigned* __restrict__ cnt, float* __restrict__ out) {
  __shared__ __align__(16) union SMem {
    struct { unsigned short Ab[BM * BKE]; unsigned short Bb[BCN * BKE]; } g;  // 24 KB
    struct { float bufA[2][1024]; float bufPN[2][2048];
             float dmP[2][64]; float dmN[2][64]; float gt[2]; float lt[2]; } d;  // ~25 KB
    float red[4];
  } sm;
  __shared__ unsigned fin;
  const int tid = threadIdx.x;
  const int lane = tid & 63;
  const int w = tid >> 6;          // wave 0..1
  const int b = blockIdx.x;

  // ---------------- phase A: Gram GEMM + mining (R2-proven body) -------------------
  {
    int ry, cx;
    tile_decode(b, ry, cx);
    const int r0 = ry * BM;
    const int c0 = cx * BCN;
    const int quad = lane >> 4;
    const int ml = lane & 15;
    const int sx = ml & 7;

    floatx4 acc[4][4];
#pragma unroll
    for (int i = 0; i < 4; ++i)
#pragma unroll
      for (int j = 0; j < 4; ++j)
#pragma unroll
        for (int k = 0; k < 4; ++k) acc[i][j][k] = 0.f;

    // staging (verified conflict-free): chunk c of row R at slot c ^ (R&7);
    // DMA lane -> (row lane>>3, slot lane&7); each async16 = 8 rows x 128 B.
    const int r_rel = lane >> 3;
    const int c_g = (lane & 7) ^ r_rel;
    const unsigned short* gA = Xbf + (size_t)(r0 + w * 64 + r_rel) * DIM + c_g * 8;
    const unsigned short* gB = Xbf + (size_t)(c0 + w * 32 + r_rel) * DIM + c_g * 8;
    unsigned short* lA = sm.g.Ab + w * 64 * BKE;
    unsigned short* lB = sm.g.Bb + w * 32 * BKE;

    for (int k0 = 0; k0 < DIM; k0 += BKE) {
      __syncthreads();
#pragma unroll
      for (int q = 0; q < 8; ++q)
        async16(gA + (size_t)(q * 8) * DIM + k0, lA + q * 8 * BKE);
#pragma unroll
      for (int q = 0; q < 4; ++q)
        async16(gB + (size_t)(q * 8) * DIM + k0, lB + q * 8 * BKE);
      __syncthreads();   // vmcnt(0) drain
#pragma unroll
      for (int h = 0; h < 2; ++h) {
        const int slot = ((h << 2) + quad) ^ sx;
        bf16x8 af[4], bfr[4];
#pragma unroll
        for (int i = 0; i < 4; ++i)
          af[i] = *(const bf16x8*)(sm.g.Ab + ((w * 64 + i * 16 + ml) * BKE) + slot * 8);
#pragma unroll
        for (int j = 0; j < 4; ++j)
          bfr[j] = *(const bf16x8*)(sm.g.Bb + ((j * 16 + ml) * BKE) + slot * 8);
#pragma unroll
        for (int i = 0; i < 4; ++i)
#pragma unroll
          for (int j = 0; j < 4; ++j)
            acc[i][j] = __builtin_amdgcn_mfma_f32_16x16x32_bf16(af[i], bfr[j], acc[i][j], 0, 0, 0);
      }
    }

    // epilogue A: row-direction mining. C/D layout: col = lane&15, row = quad*4+reg.
    const int cl = ml;
#pragma unroll
    for (int i = 0; i < 4; ++i) {
#pragma unroll
      for (int rg = 0; rg < 4; ++rg) {
        const int gr = r0 + w * 64 + i * 16 + quad * 4 + rg;
        const int tgt_r = targets[gr];
        const float sqr = sq[gr];
        unsigned long long pm = 0ULL;
        unsigned long long nm = ~0ULL;
#pragma unroll
        for (int j = 0; j < 4; ++j) {
          const int gc = c0 + j * 16 + cl;
          const float d2 = sqr + sq[gc] - 2.0f * acc[i][j][rg];
          const float dist = sqrtf(fmaxf(d2, 1e-12f));
          const unsigned long long ph = ((unsigned long long)__float_as_uint(dist)) << 32;
          if (targets[gc] == tgt_r) {
            // argmax first-index tiebreak: larger (4095-gc) == smaller gc wins
            unsigned long long cand = ph | (unsigned)(4095 - gc);
            pm = pm > cand ? pm : cand;
          } else {
            unsigned long long cand = ph | (unsigned)gc;
            nm = nm < cand ? nm : cand;
          }
        }
#pragma unroll
        for (int m = 1; m < 16; m <<= 1) {
          unsigned long long pmo = __shfl_xor(pm, m, 64);
          unsigned long long nmo = __shfl_xor(nm, m, 64);
          pm = pm > pmo ? pm : pmo;
          nm = nm < nmo ? nm : nmo;
        }
        if (cl == 0) {
          atomicMax(&posP[gr], pm);
          atomicMin(&negP[gr], nm);
        }
      }
    }

    // epilogue B: transposed mining (only when col-range outside row-range)
    if (cx >= 2 * ry + 2) {
#pragma unroll
      for (int j = 0; j < 4; ++j) {
        const int gc = c0 + j * 16 + cl;
        const int tgt_c = targets[gc];
        const float sqc = sq[gc];
        unsigned long long pm = 0ULL;
        unsigned long long nm = ~0ULL;
#pragma unroll
        for (int i = 0; i < 4; ++i) {
#pragma unroll
          for (int rg = 0; rg < 4; ++rg) {
            const int gr = r0 + w * 64 + i * 16 + quad * 4 + rg;
            const float d2 = sq[gr] + sqc - 2.0f * acc[i][j][rg];
            const float dist = sqrtf(fmaxf(d2, 1e-12f));
            const unsigned long long ph = ((unsigned long long)__float_as_uint(dist)) << 32;
            if (targets[gr] == tgt_c) {
              unsigned long long cand = ph | (unsigned)(4095 - gr);
              pm = pm > cand ? pm : cand;
            } else {
              unsigned long long cand = ph | (unsigned)gr;
              nm = nm < cand ? nm : cand;
            }
          }
        }
#pragma unroll
        for (int m = 16; m < 64; m <<= 1) {
          unsigned long long pmo = __shfl_xor(pm, m, 64);
          unsigned long long nmo = __shfl_xor(nm, m, 64);
          pm = pm > pmo ? pm : pmo;
          nm = nm < nmo ? nm : nmo;
        }
        if (quad == 0) {
          atomicMax(&posP[gc], pm);
          atomicMin(&negP[gc], nm);
        }
      }
    }
  }

  // ---------------- barrier: atomic-only handoff, NO cache fences ------------------
  __syncthreads();   // drains vmcnt: this block's mining atomics are complete
  if (tid == 0)
    __hip_atomic_fetch_add(bar, 1u, __ATOMIC_RELAXED, __HIP_MEMORY_SCOPE_AGENT);
  if (b >= 1024) return;   // non-dtw blocks arrive and exit (frees CUs)
  if (tid == 0) {
    while (__hip_atomic_load(bar, __ATOMIC_RELAXED, __HIP_MEMORY_SCOPE_AGENT) < NBLK)
      __builtin_amdgcn_s_sleep(32);
  }
  __syncthreads();

  // ---------------- phase B: local DTW (2 anchors per wave) ------------------------
  float gsum = 0.f, lsum = 0.f;
  for (int it = 0; it < 2; ++it) {
    const int a = b * 4 + w * 2 + it;
    const unsigned long long pp =
        __hip_atomic_load(&posP[a], __ATOMIC_RELAXED, __HIP_MEMORY_SCOPE_AGENT);
    const unsigned long long nn =
        __hip_atomic_load(&negP[a], __ATOMIC_RELAXED, __HIP_MEMORY_SCOPE_AGENT);
    const int p_ind = 4095 - (int)(pp & 0xFFFFFFFFULL);
    const int n_ind = (int)(nn & 0xFFFFFFFFULL);
    const float dist_ap = __uint_as_float((unsigned)(pp >> 32));
    const float dist_an = __uint_as_float((unsigned)(nn >> 32));

    const float4* ga = (const float4*)(LF + (size_t)a * 1024);
    const float4* gp = (const float4*)(LF + (size_t)p_ind * 1024);
    const float4* gn = (const float4*)(LF + (size_t)n_ind * 1024);
    float4* la = (float4*)sm.d.bufA[w];
    float4* lpn = (float4*)sm.d.bufPN[w];
#pragma unroll
    for (int i = 0; i < 4; ++i) {
      const int idx = lane + i * 64;
      la[idx] = ga[idx];
      float4 p = gp[idx];
      float4 n = gn[idx];
      // element e=idx*4+k of P goes to pn[2e], of N to pn[2e+1]
      lpn[2 * idx] = make_float4(p.x, n.x, p.y, n.y);
      lpn[2 * idx + 1] = make_float4(p.z, n.z, p.w, n.w);
    }
    __syncthreads();
    const int t1 = lane >> 3, t2 = lane & 7;
    float sp = 0.f, sn = 0.f;
#pragma unroll 8
    for (int d = 0; d < 128; ++d) {
      float xa = sm.d.bufA[w][d * 8 + t1];
      float2 pnv = *(const float2*)&sm.d.bufPN[w][2 * (d * 8 + t2)];
      float e1 = xa - pnv.x; sp += e1 * e1;
      float e2 = xa - pnv.y; sn += e2 * e2;
    }
    sm.d.dmP[w][lane] = tanhf(0.5f * sqrtf(fmaxf(sp, 1e-12f)));  // == (e^d-1)/(e^d+1)
    sm.d.dmN[w][lane] = tanhf(0.5f * sqrtf(fmaxf(sn, 1e-12f)));
    __syncthreads();
    // two serial 8x8 DPs per wave run concurrently on lanes 0 and 1
    if (lane < 2) {
      const float* dm = (lane == 0) ? sm.d.dmP[w] : sm.d.dmN[w];
      float row[8];
      row[0] = dm[0];
#pragma unroll
      for (int j = 1; j < 8; ++j) row[j] = row[j - 1] + dm[j];
#pragma unroll
      for (int i = 1; i < 8; ++i) {
        row[0] = row[0] + dm[i * 8];
#pragma unroll
        for (int j = 1; j < 8; ++j) row[j] = fminf(row[j], row[j - 1]) + dm[i * 8 + j];
      }
      if (lane == 0) sm.d.dmP[w][0] = row[7];   // reuse LDS slot to pass ap
      else sm.d.dmN[w][0] = row[7];             // an
    }
    __syncthreads();
    if (lane == 0) {
      gsum += fmaxf(dist_ap - dist_an + MARGINF, 0.f);
      lsum += fmaxf(sm.d.dmP[w][0] - sm.d.dmN[w][0] + MARGINF, 0.f);
    }
    __syncthreads();
  }
  if (lane == 0) { sm.d.gt[w] = gsum; sm.d.lt[w] = lsum; }
  __syncthreads();

  // ---------------- finalize: cnt pattern (R1-3-proven), agent-scope 8B atomics ----
  if (tid == 0) {
    float2 v = make_float2(sm.d.gt[0] + sm.d.gt[1], sm.d.lt[0] + sm.d.lt[1]);
    unsigned long long pb;
    __builtin_memcpy(&pb, &v, 8);
    __hip_atomic_store(&parts[b], pb, __ATOMIC_RELAXED, __HIP_MEMORY_SCOPE_AGENT);
    asm volatile("s_waitcnt vmcnt(0)" ::: "memory");   // parts store at coherence pt
    const unsigned old = __hip_atomic_fetch_add(cnt, 1u, __ATOMIC_RELAXED,
                                                __HIP_MEMORY_SCOPE_AGENT);
    fin = (old == 1023u) ? 1u : 0u;
  }
  __syncthreads();
  if (fin) {
    // last-arriving block: all 1024 parts are at the coherence point. Reduce.
    float g = 0.f, l = 0.f;
#pragma unroll
    for (int i = 0; i < 8; ++i) {
      unsigned long long pb = __hip_atomic_load(&parts[tid + i * 128], __ATOMIC_RELAXED,
                                                __HIP_MEMORY_SCOPE_AGENT);
      float2 v;
      __builtin_memcpy(&v, &pb, 8);
      g += v.x; l += v.y;
    }
#pragma unroll
    for (int m = 32; m > 0; m >>= 1) {
      g += __shfl_down(g, m, 64);
      l += __shfl_down(l, m, 64);
    }
    __syncthreads();
    if (lane == 0) { sm.red[w] = g; sm.red[w + 2] = l; }
    __syncthreads();
    if (tid == 0) {
      out[0] = (sm.red[0] + sm.red[1]) * (1.0f / 4096.0f);
      out[1] = (sm.red[2] + sm.red[3]) * (1.0f / 4096.0f);
    }
  }
}

extern "C" void kernel_launch(void* const* d_in, const int* in_sizes, int n_in,
                              void* d_out, int out_size, void* d_ws, size_t ws_size,
                              hipStream_t stream) {
  const float* X = (const float*)d_in[0];
  const int* targets = (const int*)d_in[1];
  const float* LF = (const float*)d_in[2];
  float* out = (float*)d_out;

  char* ws = (char*)d_ws;
  size_t off = 0;
  unsigned short* Xbf = (unsigned short*)(ws + off); off += (size_t)NS * DIM * 2;  // 16 MB
  float* sq = (float*)(ws + off); off += (size_t)NS * 4;
  off = (off + 255) & ~(size_t)255;
  unsigned long long* posP = (unsigned long long*)(ws + off); off += (size_t)NS * 8;
  unsigned long long* negP = (unsigned long long*)(ws + off); off += (size_t)NS * 8;
  unsigned long long* parts = (unsigned long long*)(ws + off); off += (size_t)1024 * 8;
  unsigned* bar = (unsigned*)(ws + off); off += 128;
  unsigned* cnt = (unsigned*)(ws + off); off += 128;

  prep_kernel<<<NS / 4, 256, 0, stream>>>(X, Xbf, sq, posP, negP, bar, cnt);
  gemm_dtw_kernel<<<NBLK, 128, 0, stream>>>(Xbf, sq, targets, LF, posP, negP,
                                            parts, bar, cnt, out);
}

// Round 9
// 182.296 us; speedup vs baseline: 2.6714x; 1.1213x over previous
//
#include <hip/hip_runtime.h>
#include <stdint.h>
#include <string.h>

#define NS 4096
#define DIM 2048
#define MARGINF 0.3f

typedef __bf16 bf16x8 __attribute__((ext_vector_type(8)));
typedef float floatx4 __attribute__((ext_vector_type(4)));

#define GLOBAL_AS __attribute__((address_space(1)))
#define LDS_AS __attribute__((address_space(3)))

__device__ __forceinline__ unsigned short f2bf_rne(float x) {
  unsigned u = __float_as_uint(x);
  u += 0x7FFFu + ((u >> 16) & 1u);
  return (unsigned short)(u >> 16);
}
__device__ __forceinline__ float bf2f(unsigned short b) {
  return __uint_as_float(((unsigned)b) << 16);
}

// ---------------- kernel 1: fp32 -> bf16 convert + row norms + init ----------------
// R9: one row per wave, ALL 8 float4 loads issued up-front into registers (8-deep
// MLP; the old load->convert->store per-iteration chain was latency-bound).
__global__ __launch_bounds__(256) void prep_kernel(
    const float* __restrict__ X, unsigned short* __restrict__ Xbf,
    float* __restrict__ sq, unsigned long long* __restrict__ posP,
    unsigned long long* __restrict__ negP, unsigned* __restrict__ cnt) {
  const int w = threadIdx.x >> 6, lane = threadIdx.x & 63;
  const int row = blockIdx.x * 4 + w;
  if (blockIdx.x == 0 && threadIdx.x == 0) *cnt = 0u;
  const float4* xr = (const float4*)(X + (size_t)row * DIM);
  ushort4* br = (ushort4*)(Xbf + (size_t)row * DIM);
  float4 v[8];
#pragma unroll
  for (int i = 0; i < 8; ++i) v[i] = xr[lane + i * 64];   // 8 loads in flight
  float s = 0.f;
  ushort4 o[8];
#pragma unroll
  for (int i = 0; i < 8; ++i) {
    o[i].x = f2bf_rne(v[i].x); o[i].y = f2bf_rne(v[i].y);
    o[i].z = f2bf_rne(v[i].z); o[i].w = f2bf_rne(v[i].w);
    // norm of the ROUNDED values so d2 is consistent with the MFMA dot
    float b0 = bf2f(o[i].x), b1 = bf2f(o[i].y), b2 = bf2f(o[i].z), b3 = bf2f(o[i].w);
    s += b0 * b0 + b1 * b1 + b2 * b2 + b3 * b3;
  }
#pragma unroll
  for (int i = 0; i < 8; ++i) br[lane + i * 64] = o[i];
#pragma unroll
  for (int m = 32; m > 0; m >>= 1) s += __shfl_down(s, m, 64);
  if (lane == 0) {
    sq[row] = s;
    posP[row] = 0ULL;
    negP[row] = ~0ULL;
  }
}

// ---------------- kernel 2: fused Gram GEMM + mining (R2-proven, 77 us) ------------
// 128x64 tiles, 1056 blocks (4.1 queued/CU — cross-block overlap is the proven
// latency-hiding mechanism for the 2-barrier loop), 2 waves per block, each wave
// a 64x64 sub-tile: 16 ds_read_b128 : 32 MFMA per K-step. Deep in-block
// pipelining on this geometry is a proven dead end (R3; m232), and in-kernel
// grid barriers cost 30-350 us (R7/R8). Triangle at 77 us == ~920 TF
// square-equivalent == the m97-structure ceiling. DO NOT TOUCH.
#define BM 128
#define BCN 64           // tile cols
#define BKE 64           // K elems staged per iter (128 B per row)
#define NBLK 1056

__device__ __forceinline__ void async16(const void* g, void* l) {
  __builtin_amdgcn_global_load_lds((GLOBAL_AS unsigned int*)g, (LDS_AS unsigned int*)l,
                                   16, 0, 0);
}

// tile id -> (ry, cx); cum(y) = y*(65-y) tiles precede row-chunk y; XCD swizzle 8x132
__device__ __forceinline__ void tile_decode(int tt, int& ry, int& cx) {
  const int t = (tt & 7) * 132 + (tt >> 3);
  int y = (int)((65.0f - sqrtf((float)(4225 - 4 * t))) * 0.5f);
  while ((y + 1) * (64 - y) <= t) ++y;   // cum(y+1) = (y+1)*(64-y)
  while (y * (65 - y) > t) --y;
  ry = y;
  cx = 2 * y + (t - y * (65 - y));
}

__global__ __launch_bounds__(128, 3) void gemm_mine_kernel(
    const unsigned short* __restrict__ Xbf, const float* __restrict__ sq,
    const int* __restrict__ targets,
    unsigned long long* __restrict__ posP, unsigned long long* __restrict__ negP) {
  int ry, cx;
  tile_decode(blockIdx.x, ry, cx);
  const int r0 = ry * BM;
  const int c0 = cx * BCN;

  __shared__ __align__(16) unsigned short Ab[BM * BKE];   // 16 KB
  __shared__ __align__(16) unsigned short Bb[BCN * BKE];  //  8 KB
  const int tid = threadIdx.x;
  const int lane = tid & 63;
  const int w = tid >> 6;          // wave 0..1: rows w*64..w*64+63, all 64 cols
  const int quad = lane >> 4;
  const int ml = lane & 15;

  floatx4 acc[4][4];
#pragma unroll
  for (int i = 0; i < 4; ++i)
#pragma unroll
    for (int j = 0; j < 4; ++j)
#pragma unroll
      for (int k = 0; k < 4; ++k) acc[i][j][k] = 0.f;

  // staging (verified conflict-free): row = 8 chunks of 16 B; chunk c of row R at
  // slot c ^ (R&7); DMA lane -> (row lane>>3, slot lane&7) so lane fetches global
  // chunk (lane&7)^((lane>>3)&7). Each async16 = 8 rows x 128 B.
  // wave w stages A rows w*64..+63 (8 issues) and B rows w*32..+31 (4 issues).
  const int r_rel = lane >> 3;
  const int c_g = (lane & 7) ^ r_rel;
  const unsigned short* gA = Xbf + (size_t)(r0 + w * 64 + r_rel) * DIM + c_g * 8;
  const unsigned short* gB = Xbf + (size_t)(c0 + w * 32 + r_rel) * DIM + c_g * 8;
  unsigned short* lA = Ab + w * 64 * BKE;
  unsigned short* lB = Bb + w * 32 * BKE;
  const int sx = ml & 7;

  for (int k0 = 0; k0 < DIM; k0 += BKE) {
    __syncthreads();
#pragma unroll
    for (int q = 0; q < 8; ++q)
      async16(gA + (size_t)(q * 8) * DIM + k0, lA + q * 8 * BKE);
#pragma unroll
    for (int q = 0; q < 4; ++q)
      async16(gB + (size_t)(q * 8) * DIM + k0, lB + q * 8 * BKE);
    __syncthreads();   // vmcnt(0) drain
#pragma unroll
    for (int h = 0; h < 2; ++h) {
      const int slot = ((h << 2) + quad) ^ sx;
      bf16x8 af[4], bfr[4];
#pragma unroll
      for (int i = 0; i < 4; ++i)
        af[i] = *(const bf16x8*)(Ab + ((w * 64 + i * 16 + ml) * BKE) + slot * 8);
#pragma unroll
      for (int j = 0; j < 4; ++j)
        bfr[j] = *(const bf16x8*)(Bb + ((j * 16 + ml) * BKE) + slot * 8);
#pragma unroll
      for (int i = 0; i < 4; ++i)
#pragma unroll
        for (int j = 0; j < 4; ++j)
          acc[i][j] = __builtin_amdgcn_mfma_f32_16x16x32_bf16(af[i], bfr[j], acc[i][j], 0, 0, 0);
    }
  }

  // epilogue A: row-direction mining. C/D layout: col = lane&15, row = quad*4+reg.
  const int cl = ml;
#pragma unroll
  for (int i = 0; i < 4; ++i) {
#pragma unroll
    for (int rg = 0; rg < 4; ++rg) {
      const int gr = r0 + w * 64 + i * 16 + quad * 4 + rg;
      const int tgt_r = targets[gr];
      const float sqr = sq[gr];
      unsigned long long pm = 0ULL;
      unsigned long long nm = ~0ULL;
#pragma unroll
      for (int j = 0; j < 4; ++j) {
        const int gc = c0 + j * 16 + cl;
        const float d2 = sqr + sq[gc] - 2.0f * acc[i][j][rg];
        const float dist = sqrtf(fmaxf(d2, 1e-12f));
        const unsigned long long ph = ((unsigned long long)__float_as_uint(dist)) << 32;
        if (targets[gc] == tgt_r) {
          // argmax first-index tiebreak: larger (4095-gc) == smaller gc wins on ties
          unsigned long long cand = ph | (unsigned)(4095 - gc);
          pm = pm > cand ? pm : cand;
        } else {
          unsigned long long cand = ph | (unsigned)gc;
          nm = nm < cand ? nm : cand;
        }
      }
#pragma unroll
      for (int m = 1; m < 16; m <<= 1) {
        unsigned long long pmo = __shfl_xor(pm, m, 64);
        unsigned long long nmo = __shfl_xor(nm, m, 64);
        pm = pm > pmo ? pm : pmo;
        nm = nm < nmo ? nm : nmo;
      }
      if (cl == 0) {
        atomicMax(&posP[gr], pm);
        atomicMin(&negP[gr], nm);
      }
    }
  }

  // epilogue B: transposed mining (only when col-range is outside the row-range;
  // for cx in {2ry, 2ry+1} both orderings already appear in row passes).
  if (cx >= 2 * ry + 2) {
#pragma unroll
    for (int j = 0; j < 4; ++j) {
      const int gc = c0 + j * 16 + cl;
      const int tgt_c = targets[gc];
      const float sqc = sq[gc];
      unsigned long long pm = 0ULL;
      unsigned long long nm = ~0ULL;
#pragma unroll
      for (int i = 0; i < 4; ++i) {
#pragma unroll
        for (int rg = 0; rg < 4; ++rg) {
          const int gr = r0 + w * 64 + i * 16 + quad * 4 + rg;
          const float d2 = sq[gr] + sqc - 2.0f * acc[i][j][rg];
          const float dist = sqrtf(fmaxf(d2, 1e-12f));
          const unsigned long long ph = ((unsigned long long)__float_as_uint(dist)) << 32;
          if (targets[gr] == tgt_c) {
            unsigned long long cand = ph | (unsigned)(4095 - gr);
            pm = pm > cand ? pm : cand;
          } else {
            unsigned long long cand = ph | (unsigned)gr;
            nm = nm < cand ? nm : cand;
          }
        }
      }
#pragma unroll
      for (int m = 16; m < 64; m <<= 1) {
        unsigned long long pmo = __shfl_xor(pm, m, 64);
        unsigned long long nmo = __shfl_xor(nm, m, 64);
        pm = pm > pmo ? pm : pmo;
        nm = nm < nmo ? nm : nmo;
      }
      if (quad == 0) {
        atomicMax(&posP[gc], pm);
        atomicMin(&negP[gc], nm);
      }
    }
  }
}

// ---------------- kernel 3: local DTW + finalize ----------------------------------
// R9: 2048 blocks x 128 threads, ONE anchor per wave (R8 showed dtw ~35 us:
// gather-latency-bound). All 12 gather float4s issued into REGISTERS first
// (12-deep MLP; R5's load->shuffle->LDS-write chain capped effective MLP at ~4),
// then LDS writes. PN interleave kept (1 b64+1 b32 per hot-loop step). Finalize
// merged via the R8-proven relaxed-agent cnt pattern: no spinning — only the
// last-arriving block reduces the 2048 partials.
__global__ __launch_bounds__(128) void dtw_fin_kernel(
    const float* __restrict__ LF, const unsigned long long* __restrict__ posP,
    const unsigned long long* __restrict__ negP,
    unsigned long long* __restrict__ parts, unsigned* __restrict__ cnt,
    float* __restrict__ out) {
  __shared__ float bufA[2][1024];
  __shared__ float bufPN[2][2048];
  __shared__ float dmP[2][64];
  __shared__ float dmN[2][64];
  __shared__ float gt[2], lt[2];
  __shared__ unsigned finflag;
  const int tid = threadIdx.x;
  const int w = tid >> 6, lane = tid & 63;
  const int a = blockIdx.x * 2 + w;
  const unsigned long long pp = posP[a];
  const unsigned long long nn = negP[a];
  const int p_ind = 4095 - (int)(pp & 0xFFFFFFFFULL);
  const int n_ind = (int)(nn & 0xFFFFFFFFULL);
  const float dist_ap = __uint_as_float((unsigned)(pp >> 32));
  const float dist_an = __uint_as_float((unsigned)(nn >> 32));

  const float4* ga = (const float4*)(LF + (size_t)a * 1024);
  const float4* gp = (const float4*)(LF + (size_t)p_ind * 1024);
  const float4* gn = (const float4*)(LF + (size_t)n_ind * 1024);
  float4 va[4], vp[4], vn[4];
#pragma unroll
  for (int i = 0; i < 4; ++i) {
    const int idx = lane + i * 64;
    va[i] = ga[idx]; vp[i] = gp[idx]; vn[i] = gn[idx];   // 12 loads in flight
  }
  float4* la = (float4*)bufA[w];
  float4* lpn = (float4*)bufPN[w];
#pragma unroll
  for (int i = 0; i < 4; ++i) {
    const int idx = lane + i * 64;
    la[idx] = va[i];
    // element e=idx*4+k of P goes to pn[2e], of N to pn[2e+1]
    lpn[2 * idx] = make_float4(vp[i].x, vn[i].x, vp[i].y, vn[i].y);
    lpn[2 * idx + 1] = make_float4(vp[i].z, vn[i].z, vp[i].w, vn[i].w);
  }
  __syncthreads();
  const int t1 = lane >> 3, t2 = lane & 7;
  float sp = 0.f, sn = 0.f;
#pragma unroll 8
  for (int d = 0; d < 128; ++d) {
    float xa = bufA[w][d * 8 + t1];
    float2 pnv = *(const float2*)&bufPN[w][2 * (d * 8 + t2)];
    float e1 = xa - pnv.x; sp += e1 * e1;
    float e2 = xa - pnv.y; sn += e2 * e2;
  }
  dmP[w][lane] = tanhf(0.5f * sqrtf(fmaxf(sp, 1e-12f)));  // == (e^d-1)/(e^d+1)
  dmN[w][lane] = tanhf(0.5f * sqrtf(fmaxf(sn, 1e-12f)));
  __syncthreads();
  // two serial 8x8 DPs per wave run concurrently on lanes 0 and 1
  if (lane < 2) {
    const float* dm = (lane == 0) ? dmP[w] : dmN[w];
    float row[8];
    row[0] = dm[0];
#pragma unroll
    for (int j = 1; j < 8; ++j) row[j] = row[j - 1] + dm[j];
#pragma unroll
    for (int i = 1; i < 8; ++i) {
      row[0] = row[0] + dm[i * 8];
#pragma unroll
      for (int j = 1; j < 8; ++j) row[j] = fminf(row[j], row[j - 1]) + dm[i * 8 + j];
    }
    if (lane == 0) dmP[w][0] = row[7];   // reuse LDS slot to pass ap
    else dmN[w][0] = row[7];             // an
  }
  __syncthreads();
  if (lane == 0) {
    gt[w] = fmaxf(dist_ap - dist_an + MARGINF, 0.f);
    lt[w] = fmaxf(dmP[w][0] - dmN[w][0] + MARGINF, 0.f);
  }
  __syncthreads();

  // finalize: R8-proven cnt pattern, relaxed agent-scope atomics, no spinning.
  if (tid == 0) {
    float2 v = make_float2(gt[0] + gt[1], lt[0] + lt[1]);
    unsigned long long pb;
    __builtin_memcpy(&pb, &v, 8);
    __hip_atomic_store(&parts[blockIdx.x], pb, __ATOMIC_RELAXED,
                       __HIP_MEMORY_SCOPE_AGENT);
    asm volatile("s_waitcnt vmcnt(0)" ::: "memory");   // parts store at coherence pt
    const unsigned old = __hip_atomic_fetch_add(cnt, 1u, __ATOMIC_RELAXED,
                                                __HIP_MEMORY_SCOPE_AGENT);
    finflag = (old == 2047u) ? 1u : 0u;
  }
  __syncthreads();
  if (finflag) {
    // last-arriving block: all 2048 parts are at the coherence point. Reduce.
    float g = 0.f, l = 0.f;
#pragma unroll
    for (int i = 0; i < 16; ++i) {
      unsigned long long pb = __hip_atomic_load(
          &parts[tid + i * 128], __ATOMIC_RELAXED, __HIP_MEMORY_SCOPE_AGENT);
      float2 v;
      __builtin_memcpy(&v, &pb, 8);
      g += v.x; l += v.y;
    }
#pragma unroll
    for (int m = 32; m > 0; m >>= 1) {
      g += __shfl_down(g, m, 64);
      l += __shfl_down(l, m, 64);
    }
    __syncthreads();
    if (lane == 0) { dmP[0][w] = g; dmN[0][w] = l; }
    __syncthreads();
    if (tid == 0) {
      out[0] = (dmP[0][0] + dmP[0][1]) * (1.0f / 4096.0f);
      out[1] = (dmN[0][0] + dmN[0][1]) * (1.0f / 4096.0f);
    }
  }
}

extern "C" void kernel_launch(void* const* d_in, const int* in_sizes, int n_in,
                              void* d_out, int out_size, void* d_ws, size_t ws_size,
                              hipStream_t stream) {
  const float* X = (const float*)d_in[0];
  const int* targets = (const int*)d_in[1];
  const float* LF = (const float*)d_in[2];
  float* out = (float*)d_out;

  char* ws = (char*)d_ws;
  size_t off = 0;
  unsigned short* Xbf = (unsigned short*)(ws + off); off += (size_t)NS * DIM * 2;  // 16 MB
  float* sq = (float*)(ws + off); off += (size_t)NS * 4;
  off = (off + 255) & ~(size_t)255;
  unsigned long long* posP = (unsigned long long*)(ws + off); off += (size_t)NS * 8;
  unsigned long long* negP = (unsigned long long*)(ws + off); off += (size_t)NS * 8;
  unsigned long long* parts = (unsigned long long*)(ws + off); off += (size_t)2048 * 8;
  unsigned* cnt = (unsigned*)(ws + off); off += 128;

  prep_kernel<<<NS / 4, 256, 0, stream>>>(X, Xbf, sq, posP, negP, cnt);
  gemm_mine_kernel<<<NBLK, 128, 0, stream>>>(Xbf, sq, targets, posP, negP);
  dtw_fin_kernel<<<NS / 2, 128, 0, stream>>>(LF, posP, negP, parts, cnt, out);
}

// Round 10
// 168.984 us; speedup vs baseline: 2.8818x; 1.0788x over previous
//
#include <hip/hip_runtime.h>
#include <stdint.h>

#define NS 4096
#define DIM 2048
#define MARGINF 0.3f

typedef __bf16 bf16x8 __attribute__((ext_vector_type(8)));
typedef float floatx4 __attribute__((ext_vector_type(4)));

#define GLOBAL_AS __attribute__((address_space(1)))
#define LDS_AS __attribute__((address_space(3)))

__device__ __forceinline__ unsigned short f2bf_rne(float x) {
  unsigned u = __float_as_uint(x);
  u += 0x7FFFu + ((u >> 16) & 1u);
  return (unsigned short)(u >> 16);
}
__device__ __forceinline__ float bf2f(unsigned short b) {
  return __uint_as_float(((unsigned)b) << 16);
}

// ---------------- kernel 1: fp32 -> bf16 convert + row norms + init ----------------
// R10 = R9's reg-staged body (8 independent loads in flight) on the R5 champion
// structure. One row per wave, pure-shfl reduction, no LDS/barriers.
__global__ __launch_bounds__(256) void prep_kernel(
    const float* __restrict__ X, unsigned short* __restrict__ Xbf,
    float* __restrict__ sq, unsigned long long* __restrict__ posP,
    unsigned long long* __restrict__ negP) {
  const int w = threadIdx.x >> 6, lane = threadIdx.x & 63;
  const int row = blockIdx.x * 4 + w;
  const float4* xr = (const float4*)(X + (size_t)row * DIM);
  ushort4* br = (ushort4*)(Xbf + (size_t)row * DIM);
  float4 v[8];
#pragma unroll
  for (int i = 0; i < 8; ++i) v[i] = xr[lane + i * 64];   // 8 loads in flight
  float s = 0.f;
  ushort4 o[8];
#pragma unroll
  for (int i = 0; i < 8; ++i) {
    o[i].x = f2bf_rne(v[i].x); o[i].y = f2bf_rne(v[i].y);
    o[i].z = f2bf_rne(v[i].z); o[i].w = f2bf_rne(v[i].w);
    // norm of the ROUNDED values so d2 is consistent with the MFMA dot
    float b0 = bf2f(o[i].x), b1 = bf2f(o[i].y), b2 = bf2f(o[i].z), b3 = bf2f(o[i].w);
    s += b0 * b0 + b1 * b1 + b2 * b2 + b3 * b3;
  }
#pragma unroll
  for (int i = 0; i < 8; ++i) br[lane + i * 64] = o[i];
#pragma unroll
  for (int m = 32; m > 0; m >>= 1) s += __shfl_down(s, m, 64);
  if (lane == 0) {
    sq[row] = s;
    posP[row] = 0ULL;
    negP[row] = ~0ULL;
  }
}

// ---------------- kernel 2: fused Gram GEMM + mining (R2-proven, 77 us) ------------
// 128x64 tiles, 1056 blocks (4.1 queued/CU — cross-block overlap is the proven
// latency-hiding mechanism for the 2-barrier loop), 2 waves per block, each wave
// a 64x64 sub-tile: 16 ds_read_b128 : 32 MFMA per K-step. Deep in-block
// pipelining on this geometry is a proven dead end (R3; m232), and in-kernel
// grid barriers cost 30-350 us (R6/R7/R8). Triangle at 77 us == ~920 TF
// square-equivalent == the m97-structure ceiling. DO NOT TOUCH.
#define BM 128
#define BCN 64           // tile cols
#define BKE 64           // K elems staged per iter (128 B per row)
#define NBLK 1056

__device__ __forceinline__ void async16(const void* g, void* l) {
  __builtin_amdgcn_global_load_lds((GLOBAL_AS unsigned int*)g, (LDS_AS unsigned int*)l,
                                   16, 0, 0);
}

// tile id -> (ry, cx); cum(y) = y*(65-y) tiles precede row-chunk y; XCD swizzle 8x132
__device__ __forceinline__ void tile_decode(int tt, int& ry, int& cx) {
  const int t = (tt & 7) * 132 + (tt >> 3);
  int y = (int)((65.0f - sqrtf((float)(4225 - 4 * t))) * 0.5f);
  while ((y + 1) * (64 - y) <= t) ++y;   // cum(y+1) = (y+1)*(64-y)
  while (y * (65 - y) > t) --y;
  ry = y;
  cx = 2 * y + (t - y * (65 - y));
}

__global__ __launch_bounds__(128, 3) void gemm_mine_kernel(
    const unsigned short* __restrict__ Xbf, const float* __restrict__ sq,
    const int* __restrict__ targets,
    unsigned long long* __restrict__ posP, unsigned long long* __restrict__ negP) {
  int ry, cx;
  tile_decode(blockIdx.x, ry, cx);
  const int r0 = ry * BM;
  const int c0 = cx * BCN;

  __shared__ __align__(16) unsigned short Ab[BM * BKE];   // 16 KB
  __shared__ __align__(16) unsigned short Bb[BCN * BKE];  //  8 KB
  const int tid = threadIdx.x;
  const int lane = tid & 63;
  const int w = tid >> 6;          // wave 0..1: rows w*64..w*64+63, all 64 cols
  const int quad = lane >> 4;
  const int ml = lane & 15;

  floatx4 acc[4][4];
#pragma unroll
  for (int i = 0; i < 4; ++i)
#pragma unroll
    for (int j = 0; j < 4; ++j)
#pragma unroll
      for (int k = 0; k < 4; ++k) acc[i][j][k] = 0.f;

  // staging (verified conflict-free): row = 8 chunks of 16 B; chunk c of row R at
  // slot c ^ (R&7); DMA lane -> (row lane>>3, slot lane&7) so lane fetches global
  // chunk (lane&7)^((lane>>3)&7). Each async16 = 8 rows x 128 B.
  // wave w stages A rows w*64..+63 (8 issues) and B rows w*32..+31 (4 issues).
  const int r_rel = lane >> 3;
  const int c_g = (lane & 7) ^ r_rel;
  const unsigned short* gA = Xbf + (size_t)(r0 + w * 64 + r_rel) * DIM + c_g * 8;
  const unsigned short* gB = Xbf + (size_t)(c0 + w * 32 + r_rel) * DIM + c_g * 8;
  unsigned short* lA = Ab + w * 64 * BKE;
  unsigned short* lB = Bb + w * 32 * BKE;
  const int sx = ml & 7;

  for (int k0 = 0; k0 < DIM; k0 += BKE) {
    __syncthreads();
#pragma unroll
    for (int q = 0; q < 8; ++q)
      async16(gA + (size_t)(q * 8) * DIM + k0, lA + q * 8 * BKE);
#pragma unroll
    for (int q = 0; q < 4; ++q)
      async16(gB + (size_t)(q * 8) * DIM + k0, lB + q * 8 * BKE);
    __syncthreads();   // vmcnt(0) drain
#pragma unroll
    for (int h = 0; h < 2; ++h) {
      const int slot = ((h << 2) + quad) ^ sx;
      bf16x8 af[4], bfr[4];
#pragma unroll
      for (int i = 0; i < 4; ++i)
        af[i] = *(const bf16x8*)(Ab + ((w * 64 + i * 16 + ml) * BKE) + slot * 8);
#pragma unroll
      for (int j = 0; j < 4; ++j)
        bfr[j] = *(const bf16x8*)(Bb + ((j * 16 + ml) * BKE) + slot * 8);
#pragma unroll
      for (int i = 0; i < 4; ++i)
#pragma unroll
        for (int j = 0; j < 4; ++j)
          acc[i][j] = __builtin_amdgcn_mfma_f32_16x16x32_bf16(af[i], bfr[j], acc[i][j], 0, 0, 0);
    }
  }

  // epilogue A: row-direction mining. C/D layout: col = lane&15, row = quad*4+reg.
  const int cl = ml;
#pragma unroll
  for (int i = 0; i < 4; ++i) {
#pragma unroll
    for (int rg = 0; rg < 4; ++rg) {
      const int gr = r0 + w * 64 + i * 16 + quad * 4 + rg;
      const int tgt_r = targets[gr];
      const float sqr = sq[gr];
      unsigned long long pm = 0ULL;
      unsigned long long nm = ~0ULL;
#pragma unroll
      for (int j = 0; j < 4; ++j) {
        const int gc = c0 + j * 16 + cl;
        const float d2 = sqr + sq[gc] - 2.0f * acc[i][j][rg];
        const float dist = sqrtf(fmaxf(d2, 1e-12f));
        const unsigned long long ph = ((unsigned long long)__float_as_uint(dist)) << 32;
        if (targets[gc] == tgt_r) {
          // argmax first-index tiebreak: larger (4095-gc) == smaller gc wins on ties
          unsigned long long cand = ph | (unsigned)(4095 - gc);
          pm = pm > cand ? pm : cand;
        } else {
          unsigned long long cand = ph | (unsigned)gc;
          nm = nm < cand ? nm : cand;
        }
      }
#pragma unroll
      for (int m = 1; m < 16; m <<= 1) {
        unsigned long long pmo = __shfl_xor(pm, m, 64);
        unsigned long long nmo = __shfl_xor(nm, m, 64);
        pm = pm > pmo ? pm : pmo;
        nm = nm < nmo ? nm : nmo;
      }
      if (cl == 0) {
        atomicMax(&posP[gr], pm);
        atomicMin(&negP[gr], nm);
      }
    }
  }

  // epilogue B: transposed mining (only when col-range is outside the row-range;
  // for cx in {2ry, 2ry+1} both orderings already appear in row passes).
  if (cx >= 2 * ry + 2) {
#pragma unroll
    for (int j = 0; j < 4; ++j) {
      const int gc = c0 + j * 16 + cl;
      const int tgt_c = targets[gc];
      const float sqc = sq[gc];
      unsigned long long pm = 0ULL;
      unsigned long long nm = ~0ULL;
#pragma unroll
      for (int i = 0; i < 4; ++i) {
#pragma unroll
        for (int rg = 0; rg < 4; ++rg) {
          const int gr = r0 + w * 64 + i * 16 + quad * 4 + rg;
          const float d2 = sq[gr] + sqc - 2.0f * acc[i][j][rg];
          const float dist = sqrtf(fmaxf(d2, 1e-12f));
          const unsigned long long ph = ((unsigned long long)__float_as_uint(dist)) << 32;
          if (targets[gr] == tgt_c) {
            unsigned long long cand = ph | (unsigned)(4095 - gr);
            pm = pm > cand ? pm : cand;
          } else {
            unsigned long long cand = ph | (unsigned)gr;
            nm = nm < cand ? nm : cand;
          }
        }
      }
#pragma unroll
      for (int m = 16; m < 64; m <<= 1) {
        unsigned long long pmo = __shfl_xor(pm, m, 64);
        unsigned long long nmo = __shfl_xor(nm, m, 64);
        pm = pm > pmo ? pm : pmo;
        nm = nm < nmo ? nm : nmo;
      }
      if (quad == 0) {
        atomicMax(&posP[gc], pm);
        atomicMin(&negP[gc], nm);
      }
    }
  }
}

// ---------------- kernel 3: local DTW distances -> per-block partial sums ----------
// R5-proven champion body: 1024 blocks x 256 threads, one anchor per wave,
// P/N interleaved in LDS (one ds_read_b64 + one b32 per hot-loop step), plain
// float2 partial per block (no contended atomics — R4's -28 us lesson).
__global__ __launch_bounds__(256) void local_dtw_kernel(
    const float* __restrict__ LF, const unsigned long long* __restrict__ posP,
    const unsigned long long* __restrict__ negP, float2* __restrict__ parts) {
  __shared__ float bufA[4][1024];
  __shared__ float bufPN[4][2048];
  __shared__ float dmP[4][64];
  __shared__ float dmN[4][64];
  __shared__ float gterms[4], lterms[4];
  const int w = threadIdx.x >> 6, lane = threadIdx.x & 63;
  const int a = blockIdx.x * 4 + w;
  const unsigned long long pp = posP[a];
  const unsigned long long nn = negP[a];
  const int p_ind = 4095 - (int)(pp & 0xFFFFFFFFULL);
  const int n_ind = (int)(nn & 0xFFFFFFFFULL);
  const float dist_ap = __uint_as_float((unsigned)(pp >> 32));
  const float dist_an = __uint_as_float((unsigned)(nn >> 32));

  const float4* ga = (const float4*)(LF + (size_t)a * 1024);
  const float4* gp = (const float4*)(LF + (size_t)p_ind * 1024);
  const float4* gn = (const float4*)(LF + (size_t)n_ind * 1024);
  float4* la = (float4*)bufA[w];
  float4* lpn = (float4*)bufPN[w];
#pragma unroll
  for (int i = 0; i < 4; ++i) {
    const int idx = lane + i * 64;
    la[idx] = ga[idx];
    float4 p = gp[idx];
    float4 n = gn[idx];
    // element e=idx*4+k of P goes to pn[2e], of N to pn[2e+1]
    lpn[2 * idx] = make_float4(p.x, n.x, p.y, n.y);
    lpn[2 * idx + 1] = make_float4(p.z, n.z, p.w, n.w);
  }
  __syncthreads();
  const int t1 = lane >> 3, t2 = lane & 7;
  float sp = 0.f, sn = 0.f;
#pragma unroll 8
  for (int d = 0; d < 128; ++d) {
    float xa = bufA[w][d * 8 + t1];
    float2 pnv = *(const float2*)&bufPN[w][2 * (d * 8 + t2)];
    float e1 = xa - pnv.x; sp += e1 * e1;
    float e2 = xa - pnv.y; sn += e2 * e2;
  }
  dmP[w][lane] = tanhf(0.5f * sqrtf(fmaxf(sp, 1e-12f)));  // == (e^d-1)/(e^d+1)
  dmN[w][lane] = tanhf(0.5f * sqrtf(fmaxf(sn, 1e-12f)));
  __syncthreads();
  // two serial 8x8 DPs per wave run concurrently on lanes 0 and 1
  if (lane < 2) {
    const float* dm = (lane == 0) ? dmP[w] : dmN[w];
    float row[8];
    row[0] = dm[0];
#pragma unroll
    for (int j = 1; j < 8; ++j) row[j] = row[j - 1] + dm[j];
#pragma unroll
    for (int i = 1; i < 8; ++i) {
      row[0] = row[0] + dm[i * 8];
#pragma unroll
      for (int j = 1; j < 8; ++j) row[j] = fminf(row[j], row[j - 1]) + dm[i * 8 + j];
    }
    if (lane == 0) dmP[w][0] = row[7];   // reuse LDS slot to pass ap
    else dmN[w][0] = row[7];             // an
  }
  __syncthreads();
  if (lane == 0) {
    gterms[w] = fmaxf(dist_ap - dist_an + MARGINF, 0.f);
    lterms[w] = fmaxf(dmP[w][0] - dmN[w][0] + MARGINF, 0.f);
  }
  __syncthreads();
  if (threadIdx.x == 0) {
    parts[blockIdx.x] = make_float2(gterms[0] + gterms[1] + gterms[2] + gterms[3],
                                    lterms[0] + lterms[1] + lterms[2] + lterms[3]);
  }
}

// ---------------- kernel 4: finalize — reduce 1024 partials, write out -------------
__global__ __launch_bounds__(256) void finalize_kernel(
    const float2* __restrict__ parts, float* __restrict__ out) {
  const int t = threadIdx.x;
  float g = 0.f, l = 0.f;
#pragma unroll
  for (int i = 0; i < 4; ++i) {
    float2 v = parts[t + i * 256];
    g += v.x; l += v.y;
  }
#pragma unroll
  for (int m = 32; m > 0; m >>= 1) {
    g += __shfl_down(g, m, 64);
    l += __shfl_down(l, m, 64);
  }
  __shared__ float sg[4], sl[4];
  if ((t & 63) == 0) { sg[t >> 6] = g; sl[t >> 6] = l; }
  __syncthreads();
  if (t == 0) {
    out[0] = (sg[0] + sg[1] + sg[2] + sg[3]) * (1.0f / 4096.0f);
    out[1] = (sl[0] + sl[1] + sl[2] + sl[3]) * (1.0f / 4096.0f);
  }
}

extern "C" void kernel_launch(void* const* d_in, const int* in_sizes, int n_in,
                              void* d_out, int out_size, void* d_ws, size_t ws_size,
                              hipStream_t stream) {
  const float* X = (const float*)d_in[0];
  const int* targets = (const int*)d_in[1];
  const float* LF = (const float*)d_in[2];
  float* out = (float*)d_out;

  char* ws = (char*)d_ws;
  size_t off = 0;
  unsigned short* Xbf = (unsigned short*)(ws + off); off += (size_t)NS * DIM * 2;  // 16 MB
  float* sq = (float*)(ws + off); off += (size_t)NS * 4;
  off = (off + 255) & ~(size_t)255;
  unsigned long long* posP = (unsigned long long*)(ws + off); off += (size_t)NS * 8;
  unsigned long long* negP = (unsigned long long*)(ws + off); off += (size_t)NS * 8;
  float2* parts = (float2*)(ws + off); off += (size_t)1024 * 8;

  prep_kernel<<<NS / 4, 256, 0, stream>>>(X, Xbf, sq, posP, negP);
  gemm_mine_kernel<<<NBLK, 128, 0, stream>>>(Xbf, sq, targets, posP, negP);
  local_dtw_kernel<<<NS / 4, 256, 0, stream>>>(LF, posP, negP, parts);
  finalize_kernel<<<1, 256, 0, stream>>>(parts, out);
}